// Round 1
// baseline (274.923 us; speedup 1.0000x reference)
//
#include <hip/hip_runtime.h>
#include <hip/hip_bf16.h>
#include <math.h>

typedef __attribute__((ext_vector_type(8))) short short8;
typedef __attribute__((ext_vector_type(4))) float float4v;

#define BATCH 8
#define SEQ   4096
#define DIM   768
#define HID   512
#define M_TOK (BATCH * SEQ)   // 32768

// ---------- helpers ----------
static __device__ __forceinline__ short f2bf(float x) {
    unsigned int u = __float_as_uint(x);
    unsigned int r = (u + 0x7FFFu + ((u >> 16) & 1u)) >> 16;   // RNE
    return (short)r;
}

// ---------- prep: transpose W1 -> W1T (bf16, [HID][DIM]), zero logits & counter ----------
__global__ __launch_bounds__(256) void prep_kernel(const float* __restrict__ W1,
                                                   short* __restrict__ W1T,
                                                   float* __restrict__ logits,
                                                   int* __restrict__ nbtot) {
    int idx = blockIdx.x * 256 + threadIdx.x;        // 0 .. DIM*HID-1
    if (idx < DIM * HID) {
        int k = idx / HID, n = idx % HID;            // W1 row-major [DIM][HID]
        W1T[n * DIM + k] = f2bf(W1[idx]);
    }
    if (idx < M_TOK) logits[idx] = 0.f;
    if (idx == 0) *nbtot = 0;
}

// ---------- MLP GEMM: logits_partial += sum_n relu(A.W1 + b1) * W2 ----------
// A [M_TOK][DIM] fp32, BT = W1^T [HID][DIM] bf16. Tile 128(M) x 128(N), BK=32.
__global__ __launch_bounds__(256) void mlp_kernel(const float* __restrict__ A,
                                                  const short* __restrict__ BT,
                                                  const float* __restrict__ b1,
                                                  const float* __restrict__ W2,
                                                  float* __restrict__ logits) {
    __shared__ short As[128 * 40];   // +8 pad per 32-row: 2-way banks only
    __shared__ short Bs[128 * 40];

    const int n0 = blockIdx.x * 128;     // n-tile fastest-varying -> A-tile L3 reuse
    const int m0 = blockIdx.y * 128;
    const int tid  = threadIdx.x;
    const int srow = tid >> 1;           // 0..127
    const int shalf = tid & 1;           // 0..1 (16-element half of the 32-wide K chunk)
    const int wave = tid >> 6, lane = tid & 63;
    const int quad = lane >> 4, r = lane & 15;
    const int waveM = (wave & 1) * 64, waveN = (wave >> 1) * 64;

    float4v acc[4][4] = {};

    const float* aRow = A + (size_t)(m0 + srow) * DIM;
    const short* bRow = BT + (size_t)(n0 + srow) * DIM;

    for (int k0 = 0; k0 < DIM; k0 += 32) {
        // global loads (before barrier so they overlap the previous compute drain)
        const float* ap = aRow + k0 + shalf * 16;
        float4v f0 = *(const float4v*)(ap + 0);
        float4v f1 = *(const float4v*)(ap + 4);
        float4v f2 = *(const float4v*)(ap + 8);
        float4v f3 = *(const float4v*)(ap + 12);
        const short* bp = bRow + k0 + shalf * 16;
        short8 g0 = *(const short8*)(bp + 0);
        short8 g1 = *(const short8*)(bp + 8);

        __syncthreads();   // previous iteration's LDS reads done

        short cv[16];
#pragma unroll
        for (int i = 0; i < 4; i++) {
            cv[i]      = f2bf(f0[i]);
            cv[4 + i]  = f2bf(f1[i]);
            cv[8 + i]  = f2bf(f2[i]);
            cv[12 + i] = f2bf(f3[i]);
        }
        *(short8*)(&As[srow * 40 + shalf * 16])     = *(short8*)&cv[0];
        *(short8*)(&As[srow * 40 + shalf * 16 + 8]) = *(short8*)&cv[8];
        *(short8*)(&Bs[srow * 40 + shalf * 16])     = g0;
        *(short8*)(&Bs[srow * 40 + shalf * 16 + 8]) = g1;

        __syncthreads();

        short8 af[4], bf[4];
#pragma unroll
        for (int i = 0; i < 4; i++) {
            af[i] = *(const short8*)(&As[(waveM + i * 16 + r) * 40 + quad * 8]);
            bf[i] = *(const short8*)(&Bs[(waveN + i * 16 + r) * 40 + quad * 8]);
        }
#pragma unroll
        for (int mi = 0; mi < 4; mi++)
#pragma unroll
            for (int ni = 0; ni < 4; ni++)
                acc[mi][ni] = __builtin_amdgcn_mfma_f32_16x16x32_bf16(
                    af[mi], bf[ni], acc[mi][ni], 0, 0, 0);
    }

    // epilogue: h = relu(acc + b1[col]); partial logit = sum_cols h * W2[col]
    float w2v[4], b1v[4];
#pragma unroll
    for (int ni = 0; ni < 4; ni++) {
        int gc = n0 + waveN + ni * 16 + r;
        w2v[ni] = W2[gc];
        b1v[ni] = b1[gc];
    }
#pragma unroll
    for (int mi = 0; mi < 4; mi++) {
#pragma unroll
        for (int v = 0; v < 4; v++) {
            float p = 0.f;
#pragma unroll
            for (int ni = 0; ni < 4; ni++) {
                float h = acc[mi][ni][v] + b1v[ni];
                h = h > 0.f ? h : 0.f;
                p += h * w2v[ni];
            }
            // reduce the 16 lanes (r = 0..15) of this quad
#pragma unroll
            for (int off = 1; off < 16; off <<= 1) p += __shfl_xor(p, off, 64);
            if (r == 0) {
                int gr = m0 + waveM + mi * 16 + quad * 4 + v;
                atomicAdd(&logits[gr], p);
            }
        }
    }
}

// ---------- boundary: hard bits, per-batch scan -> segment starts ----------
__global__ __launch_bounds__(1024) void boundary_kernel(const float* __restrict__ logits,
                                                        const float* __restrict__ b2p,
                                                        const float* __restrict__ noise,
                                                        int* __restrict__ starts,   // [BATCH][SEQ+1]
                                                        int* __restrict__ nseg,     // [BATCH]
                                                        int* __restrict__ nbtot) {
    const int b = blockIdx.x, tid = threadIdx.x;
    const int base = tid * 4;
    const float b2 = b2p[0];
    int h[4], c = 0;
#pragma unroll
    for (int j = 0; j < 4; j++) {
        int l = base + j;
        float u = noise[b * SEQ + l];
        float nz = logf(u) - log1pf(-u);
        float lg = logits[b * SEQ + l] + b2 + nz;
        h[j] = (lg > 0.f) ? 1 : 0;
        c += h[j];
    }
    const int lane = tid & 63, wid = tid >> 6;
    int inc = c;
    for (int off = 1; off < 64; off <<= 1) {
        int t = __shfl_up(inc, off, 64);
        if (lane >= off) inc += t;
    }
    __shared__ int wtot[16], woff[16], extra[2];
    if (lane == 63) wtot[wid] = inc;
    if (tid == 1023) extra[0] = h[3];
    __syncthreads();
    if (tid == 0) {
        int s = 0;
        for (int i = 0; i < 16; i++) { woff[i] = s; s += wtot[i]; }
        extra[1] = s;
    }
    __syncthreads();
    int run = (inc - c) + woff[wid];       // exclusive prefix of hard bits
#pragma unroll
    for (int j = 0; j < 4; j++) {
        int l = base + j;
        if (h[j]) {
            run++;                          // inclusive count at l == id of next segment
            if (l < SEQ - 1) starts[b * (SEQ + 1) + run] = l + 1;
        }
    }
    if (tid == 0) {
        int total = extra[1];
        int ns = total + (extra[0] ? 0 : 1);
        starts[b * (SEQ + 1)] = 0;
        starts[b * (SEQ + 1) + ns] = SEQ;
        nseg[b] = ns;
        atomicAdd(nbtot, total);
    }
}

// ---------- pool: one wave per (segment slot, batch); zero-fill unused slots ----------
__global__ __launch_bounds__(64) void pool_kernel(const float* __restrict__ hidden,
                                                  const int* __restrict__ starts,
                                                  const int* __restrict__ nseg,
                                                  float* __restrict__ out) {
    const int s = blockIdx.x, b = blockIdx.y;
    const int lane = threadIdx.x;
    float* orow = out + (size_t)(b * SEQ + s) * DIM;
    const int ns = nseg[b];
    if (s >= ns) {
        float4v z = {0.f, 0.f, 0.f, 0.f};
        *(float4v*)(orow + lane * 4)         = z;
        *(float4v*)(orow + (lane + 64) * 4)  = z;
        *(float4v*)(orow + (lane + 128) * 4) = z;
        return;
    }
    const int st = starts[b * (SEQ + 1) + s];
    const int en = starts[b * (SEQ + 1) + s + 1];
    float4v a0 = {0.f, 0.f, 0.f, 0.f}, a1 = a0, a2 = a0;
    const float* hbase = hidden + (size_t)(b * SEQ) * DIM;
    for (int row = st; row < en; row++) {
        const float* hr = hbase + (size_t)row * DIM;
        a0 += *(const float4v*)(hr + lane * 4);
        a1 += *(const float4v*)(hr + (lane + 64) * 4);
        a2 += *(const float4v*)(hr + (lane + 128) * 4);
    }
    const float invc = 1.f / (float)(en - st);
    a0 *= invc; a1 *= invc; a2 *= invc;
    *(float4v*)(orow + lane * 4)         = a0;
    *(float4v*)(orow + (lane + 64) * 4)  = a1;
    *(float4v*)(orow + (lane + 128) * 4) = a2;
}

// ---------- finalize: loss / num_boundaries / total_positions ----------
__global__ void finalize_kernel(const int* __restrict__ nbtot, float* __restrict__ tail) {
    int nb = *nbtot;
    float ratio = (float)nb / (float)M_TOK;
    float d = fabsf(ratio - 0.25f) - 0.05f;    // PRIOR + 0.05 = 0.25, margin 0.05
    tail[0] = d > 0.f ? d : 0.f;
    tail[1] = (float)nb;
    tail[2] = (float)M_TOK;
}

// ---------- launch ----------
extern "C" void kernel_launch(void* const* d_in, const int* in_sizes, int n_in,
                              void* d_out, int out_size, void* d_ws, size_t ws_size,
                              hipStream_t stream) {
    const float* hidden = (const float*)d_in[0];
    const float* W1     = (const float*)d_in[1];
    const float* b1     = (const float*)d_in[2];
    const float* W2     = (const float*)d_in[3];
    const float* b2     = (const float*)d_in[4];
    const float* noise  = (const float*)d_in[5];

    char* ws = (char*)d_ws;
    short* W1T    = (short*)(ws);                          // 512*768*2      = 786432 B
    float* logits = (float*)(ws + 786432);                 // 32768*4        = 131072 B
    int*   starts = (int*)(ws + 917504);                   // 8*4097*4       = 131104 B
    int*   nseg   = (int*)(ws + 917504 + 131104);          // 8*4
    int*   nbtot  = nseg + 8;                              // 4
    float* out    = (float*)d_out;

    prep_kernel<<<1536, 256, 0, stream>>>(W1, W1T, logits, nbtot);
    mlp_kernel<<<dim3(4, 256), 256, 0, stream>>>(hidden, W1T, b1, W2, logits);
    boundary_kernel<<<BATCH, 1024, 0, stream>>>(logits, b2, noise, starts, nseg, nbtot);
    pool_kernel<<<dim3(SEQ, BATCH), 64, 0, stream>>>(hidden, starts, nseg, out);
    finalize_kernel<<<1, 1, 0, stream>>>(nbtot, out + (size_t)M_TOK * DIM);
}

// Round 2
// 256.227 us; speedup vs baseline: 1.0730x; 1.0730x over previous
//
#include <hip/hip_runtime.h>
#include <math.h>

typedef __attribute__((ext_vector_type(8))) short short8;
typedef __attribute__((ext_vector_type(4))) float float4v;
typedef unsigned int uint;

#define BATCH 8
#define SEQ   4096
#define DIM   768
#define HID   512
#define M_TOK (BATCH * SEQ)   // 32768

// ---------- helpers ----------
static __device__ __forceinline__ short f2bf_rne(float x) {
    unsigned int u = __float_as_uint(x);
    unsigned int r = (u + 0x7FFFu + ((u >> 16) & 1u)) >> 16;   // RNE
    return (short)r;
}
// pack two floats -> 2 bf16 (truncate) in ONE v_perm_b32. lo=bf16(a), hi=bf16(b).
static __device__ __forceinline__ uint pack_bf2(float a, float b) {
    return __builtin_amdgcn_perm(__float_as_uint(b), __float_as_uint(a), 0x07060302u);
}

// ---------- prep: transpose W1 -> W1T (bf16, [HID][DIM]) ----------
__global__ __launch_bounds__(256) void prep_kernel(const float* __restrict__ W1,
                                                   short* __restrict__ W1T) {
    int idx = blockIdx.x * 256 + threadIdx.x;        // 0 .. DIM*HID-1
    if (idx < DIM * HID) {
        int k = idx / HID, n = idx % HID;            // W1 row-major [DIM][HID]
        W1T[n * DIM + k] = f2bf_rne(W1[idx]);
    }
}

// ---------- MLP GEMM: partial[buf][row] = sum over 64-col slice of relu(A.W1+b1)*W2 ----------
// A [M_TOK][DIM] fp32, BT = W1^T [HID][DIM] bf16. Tile 128(M) x 128(N), BK=32.
// Register ping-pong prefetch; perm-pack fp32->bf16; XCD-swizzled block id so the
// 4 sibling n-blocks of one m-tile land on ONE XCD (A-tile 393 KB fits its 4 MB L2).
__global__ __launch_bounds__(256) void mlp_kernel(const float* __restrict__ A,
                                                  const short* __restrict__ BT,
                                                  const float* __restrict__ b1,
                                                  const float* __restrict__ W2,
                                                  float* __restrict__ partial) {
    __shared__ short As[128 * 40];   // pad 40: frag reads land 2-way on banks (free)
    __shared__ short Bs[128 * 40];

    const int id  = blockIdx.x;
    // siblings (same m-tile, n=0..3) share id%8 -> same XCD under round-robin dispatch
    const int m_t = (id & 7) + ((id >> 5) << 3);
    const int n_t = (id >> 3) & 3;
    const int m0 = m_t << 7, n0 = n_t << 7;

    const int tid  = threadIdx.x;
    const int srow = tid >> 1;           // 0..127
    const int shalf = tid & 1;           // which 16-wide half of the 32-wide K chunk
    const int wave = tid >> 6, lane = tid & 63;
    const int quad = lane >> 4, r = lane & 15;
    const int waveM = (wave & 1) << 6, waveN = (wave >> 1) << 6;

    float4v acc[4][4] = {};

    const float* aRow = A + (size_t)(m0 + srow) * DIM + shalf * 16;
    const short* bRow = BT + (size_t)(n0 + srow) * DIM + shalf * 16;

    const int lw = srow * 40 + shalf * 16;
    const int la = (waveM + r) * 40 + quad * 8;
    const int lb = (waveN + r) * 40 + quad * 8;

    float4v fA[2][4];
    short8  fB[2][2];
#pragma unroll
    for (int i = 0; i < 4; i++) fA[0][i] = *(const float4v*)(aRow + i * 4);
    fB[0][0] = *(const short8*)(bRow);
    fB[0][1] = *(const short8*)(bRow + 8);

#pragma unroll
    for (int it = 0; it < 24; ++it) {
        const int cur = it & 1;
        // issue NEXT chunk's global loads first — they fly during this whole iteration
        if (it + 1 < 24) {
            const float* ap = aRow + (it + 1) * 32;
            const short* bp = bRow + (it + 1) * 32;
#pragma unroll
            for (int i = 0; i < 4; i++) fA[cur ^ 1][i] = *(const float4v*)(ap + i * 4);
            fB[cur ^ 1][0] = *(const short8*)(bp);
            fB[cur ^ 1][1] = *(const short8*)(bp + 8);
        }
        // pack current A chunk (1 v_perm per 2 elems)
        uint pk[8];
#pragma unroll
        for (int i = 0; i < 4; i++) {
            pk[2 * i]     = pack_bf2(fA[cur][i][0], fA[cur][i][1]);
            pk[2 * i + 1] = pack_bf2(fA[cur][i][2], fA[cur][i][3]);
        }
        __syncthreads();   // previous iteration's LDS reads done
        *(short8*)(&As[lw])     = *(short8*)&pk[0];
        *(short8*)(&As[lw + 8]) = *(short8*)&pk[4];
        *(short8*)(&Bs[lw])     = fB[cur][0];
        *(short8*)(&Bs[lw + 8]) = fB[cur][1];
        __syncthreads();

        short8 af[4], bf[4];
#pragma unroll
        for (int i = 0; i < 4; i++) {
            af[i] = *(const short8*)(&As[la + i * 16 * 40]);
            bf[i] = *(const short8*)(&Bs[lb + i * 16 * 40]);
        }
#pragma unroll
        for (int mi = 0; mi < 4; mi++)
#pragma unroll
            for (int ni = 0; ni < 4; ni++)
                acc[mi][ni] = __builtin_amdgcn_mfma_f32_16x16x32_bf16(
                    af[mi], bf[ni], acc[mi][ni], 0, 0, 0);
    }

    // epilogue: h = relu(acc + b1[col]); partial logit = sum_cols h * W2[col]
    float w2v[4], b1v[4];
#pragma unroll
    for (int ni = 0; ni < 4; ni++) {
        int gc = n0 + waveN + ni * 16 + r;
        w2v[ni] = W2[gc];
        b1v[ni] = b1[gc];
    }
    const int buf = n_t * 2 + (waveN >> 6);    // 8 deterministic partial buffers
#pragma unroll
    for (int mi = 0; mi < 4; mi++) {
#pragma unroll
        for (int v = 0; v < 4; v++) {
            float p = 0.f;
#pragma unroll
            for (int ni = 0; ni < 4; ni++) {
                float h = acc[mi][ni][v] + b1v[ni];
                h = h > 0.f ? h : 0.f;
                p += h * w2v[ni];
            }
#pragma unroll
            for (int off = 1; off < 16; off <<= 1) p += __shfl_xor(p, off, 64);
            if (r == 0) {
                int gr = m0 + waveM + mi * 16 + quad * 4 + v;
                partial[(size_t)buf * M_TOK + gr] = p;   // no atomics, no zero-init
            }
        }
    }
}

// ---------- boundary: sum partials -> logit, hard bits, per-batch scan -> segment starts ----------
__global__ __launch_bounds__(1024) void boundary_kernel(const float* __restrict__ partial,
                                                        const float* __restrict__ b2p,
                                                        const float* __restrict__ noise,
                                                        int* __restrict__ starts,   // [BATCH][SEQ+1]
                                                        int* __restrict__ nseg,     // [BATCH]
                                                        int* __restrict__ nbcount) {// [BATCH]
    const int b = blockIdx.x, tid = threadIdx.x;
    const int base = tid * 4;
    const float b2 = b2p[0];
    int h[4], c = 0;
#pragma unroll
    for (int j = 0; j < 4; j++) {
        int l = base + j;
        float u = noise[b * SEQ + l];
        float nz = logf(u) - log1pf(-u);
        float lg = b2 + nz;
#pragma unroll
        for (int q = 0; q < 8; q++) lg += partial[(size_t)q * M_TOK + b * SEQ + l];
        h[j] = (lg > 0.f) ? 1 : 0;
        c += h[j];
    }
    const int lane = tid & 63, wid = tid >> 6;
    int inc = c;
    for (int off = 1; off < 64; off <<= 1) {
        int t = __shfl_up(inc, off, 64);
        if (lane >= off) inc += t;
    }
    __shared__ int wtot[16], woff[16], extra[2];
    if (lane == 63) wtot[wid] = inc;
    if (tid == 1023) extra[0] = h[3];
    __syncthreads();
    if (tid == 0) {
        int s = 0;
        for (int i = 0; i < 16; i++) { woff[i] = s; s += wtot[i]; }
        extra[1] = s;
    }
    __syncthreads();
    int run = (inc - c) + woff[wid];       // exclusive prefix of hard bits
#pragma unroll
    for (int j = 0; j < 4; j++) {
        int l = base + j;
        if (h[j]) {
            run++;                          // inclusive count at l == id of next segment
            if (l < SEQ - 1) starts[b * (SEQ + 1) + run] = l + 1;
        }
    }
    if (tid == 0) {
        int total = extra[1];
        int ns = total + (extra[0] ? 0 : 1);
        starts[b * (SEQ + 1)] = 0;
        starts[b * (SEQ + 1) + ns] = SEQ;
        nseg[b] = ns;
        nbcount[b] = total;                 // no atomics
    }
}

// ---------- pool: 4 waves/block, one wave per segment slot; zero-fill unused slots ----------
__global__ __launch_bounds__(256) void pool_kernel(const float* __restrict__ hidden,
                                                   const int* __restrict__ starts,
                                                   const int* __restrict__ nseg,
                                                   float* __restrict__ out) {
    const int wid = threadIdx.x >> 6, lane = threadIdx.x & 63;
    const int s = blockIdx.x * 4 + wid, b = blockIdx.y;
    float* orow = out + (size_t)(b * SEQ + s) * DIM;
    const int ns = nseg[b];
    if (s >= ns) {
        float4v z = {0.f, 0.f, 0.f, 0.f};
        *(float4v*)(orow + lane * 4)         = z;
        *(float4v*)(orow + (lane + 64) * 4)  = z;
        *(float4v*)(orow + (lane + 128) * 4) = z;
        return;
    }
    const int st = starts[b * (SEQ + 1) + s];
    const int en = starts[b * (SEQ + 1) + s + 1];
    float4v a0 = {0.f, 0.f, 0.f, 0.f}, a1 = a0, a2 = a0;
    const float* hbase = hidden + (size_t)(b * SEQ) * DIM;
    for (int row = st; row < en; row++) {
        const float* hr = hbase + (size_t)row * DIM;
        a0 += *(const float4v*)(hr + lane * 4);
        a1 += *(const float4v*)(hr + (lane + 64) * 4);
        a2 += *(const float4v*)(hr + (lane + 128) * 4);
    }
    const float invc = 1.f / (float)(en - st);
    a0 *= invc; a1 *= invc; a2 *= invc;
    *(float4v*)(orow + lane * 4)         = a0;
    *(float4v*)(orow + (lane + 64) * 4)  = a1;
    *(float4v*)(orow + (lane + 128) * 4) = a2;
}

// ---------- finalize: loss / num_boundaries / total_positions ----------
__global__ void finalize_kernel(const int* __restrict__ nbcount, float* __restrict__ tail) {
    int nb = 0;
    for (int i = 0; i < BATCH; i++) nb += nbcount[i];
    float ratio = (float)nb / (float)M_TOK;
    float d = fabsf(ratio - 0.25f) - 0.05f;    // PRIOR + 0.05 = 0.25, margin 0.05
    tail[0] = d > 0.f ? d : 0.f;
    tail[1] = (float)nb;
    tail[2] = (float)M_TOK;
}

// ---------- launch ----------
extern "C" void kernel_launch(void* const* d_in, const int* in_sizes, int n_in,
                              void* d_out, int out_size, void* d_ws, size_t ws_size,
                              hipStream_t stream) {
    const float* hidden = (const float*)d_in[0];
    const float* W1     = (const float*)d_in[1];
    const float* b1     = (const float*)d_in[2];
    const float* W2     = (const float*)d_in[3];
    const float* b2     = (const float*)d_in[4];
    const float* noise  = (const float*)d_in[5];

    char* ws = (char*)d_ws;
    short* W1T     = (short*)(ws);                         // 786432 B
    float* partial = (float*)(ws + 786432);                // 8*32768*4 = 1048576 B
    int*   starts  = (int*)(ws + 786432 + 1048576);        // 8*4097*4  = 131104 B
    int*   nseg    = (int*)(ws + 786432 + 1048576 + 131104);
    int*   nbcount = nseg + 8;
    float* out     = (float*)d_out;

    prep_kernel<<<1536, 256, 0, stream>>>(W1, W1T);
    mlp_kernel<<<1024, 256, 0, stream>>>(hidden, W1T, b1, W2, partial);
    boundary_kernel<<<BATCH, 1024, 0, stream>>>(partial, b2, noise, starts, nseg, nbcount);
    pool_kernel<<<dim3(SEQ / 4, BATCH), 256, 0, stream>>>(hidden, starts, nseg, out);
    finalize_kernel<<<1, 1, 0, stream>>>(nbcount, out + (size_t)M_TOK * DIM);
}